// Round 2
// baseline (369.652 us; speedup 1.0000x reference)
//
#include <hip/hip_runtime.h>
#include <hip/hip_bf16.h>

// ECE loss, train path:
//   conf[r]  = max(softmax(logits[r,:])) = 1 / sum(exp(l - max))
//   pred[r]  = argmax(logits[r,:])   (first index on ties, matches jnp.argmax)
//   bin      = clip(ceil(conf*10)-1, 0, 9)
//   ece      = sum_b |conf_sum/cnt - corr_sum/cnt| * cnt/N   over non-empty bins
//
// Memory-bound: 256 MB logits + 4 MB labels, floor ~41 us at 6.3 TB/s.

#define N_BINS 10
#define C 64

__global__ void ece_init_ws(double* ws) {
    int t = threadIdx.x;
    if (t < 3 * N_BINS) ws[t] = 0.0;
}

__global__ __launch_bounds__(256) void ece_rows(const float* __restrict__ logits,
                                                const int* __restrict__ labels,
                                                double* __restrict__ gbins,
                                                int N) {
    __shared__ float s_cnt[N_BINS];
    __shared__ float s_conf[N_BINS];
    __shared__ float s_corr[N_BINS];
    const int tid = threadIdx.x;
    if (tid < N_BINS) {
        s_cnt[tid] = 0.0f;
        s_conf[tid] = 0.0f;
        s_corr[tid] = 0.0f;
    }
    __syncthreads();

    const int lane16 = tid & 15;                               // position within 16-lane row group
    const int group0 = (blockIdx.x * blockDim.x + tid) >> 4;   // first row for this group
    const int ngroups = (gridDim.x * blockDim.x) >> 4;

    for (int row = group0; row < N; row += ngroups) {
        // 16 lanes x float4 = one full 64-float row, perfectly coalesced (256 B/row).
        const float4 v = reinterpret_cast<const float4*>(logits + (size_t)row * C)[lane16];

        // per-lane max + argmax (first index wins on ties)
        float m = v.x; int mi = 0;
        if (v.y > m) { m = v.y; mi = 1; }
        if (v.z > m) { m = v.z; mi = 2; }
        if (v.w > m) { m = v.w; mi = 3; }
        int idx = (lane16 << 2) + mi;

        // 16-lane butterfly max/argmax (xor masks < 16 stay within the group)
        #pragma unroll
        for (int off = 1; off < 16; off <<= 1) {
            float om = __shfl_xor(m, off, 64);
            int   oi = __shfl_xor(idx, off, 64);
            if (om > m || (om == m && oi < idx)) { m = om; idx = oi; }
        }

        // sum of exp(l - max); conf = 1/sum  (== max of softmax)
        float se = __expf(v.x - m) + __expf(v.y - m) + __expf(v.z - m) + __expf(v.w - m);
        #pragma unroll
        for (int off = 1; off < 16; off <<= 1) se += __shfl_xor(se, off, 64);

        if (lane16 == 0) {
            float conf = 1.0f / se;
            int bin = (int)ceilf(conf * (float)N_BINS) - 1;
            bin = min(max(bin, 0), N_BINS - 1);
            int lbl = labels[row];
            atomicAdd(&s_cnt[bin], 1.0f);
            atomicAdd(&s_conf[bin], conf);
            if (idx == lbl) atomicAdd(&s_corr[bin], 1.0f);
        }
    }
    __syncthreads();
    if (tid < N_BINS) {
        // flush block partials (magnitude ~500) into double global accumulators
        if (s_cnt[tid] != 0.0f) {
            atomicAdd(&gbins[tid], (double)s_cnt[tid]);
            atomicAdd(&gbins[N_BINS + tid], (double)s_conf[tid]);
            atomicAdd(&gbins[2 * N_BINS + tid], (double)s_corr[tid]);
        }
    }
}

__global__ void ece_final(const double* __restrict__ gbins, float* __restrict__ out, int N) {
    if (threadIdx.x == 0) {
        double ece = 0.0;
        for (int b = 0; b < N_BINS; ++b) {
            double cnt = gbins[b];
            if (cnt > 0.0) {
                double conf = gbins[N_BINS + b] / cnt;
                double corr = gbins[2 * N_BINS + b] / cnt;
                double d = conf - corr;
                if (d < 0.0) d = -d;
                ece += d * (cnt / (double)N);
            }
        }
        out[0] = (float)ece;
    }
}

extern "C" void kernel_launch(void* const* d_in, const int* in_sizes, int n_in,
                              void* d_out, int out_size, void* d_ws, size_t ws_size,
                              hipStream_t stream) {
    const float* logits = (const float*)d_in[0];
    const int* labels = (const int*)d_in[1];
    // d_in[2] is `train` (static 1) — unused, the train branch is baked in at trace time.
    float* out = (float*)d_out;
    double* gbins = (double*)d_ws;

    const int N = in_sizes[1];  // 1,000,000 rows (labels count)

    ece_init_ws<<<1, 64, 0, stream>>>(gbins);
    // 2048 blocks x 256 threads = 32768 row-groups (8 blocks/CU = 32 waves/CU, max occupancy).
    ece_rows<<<2048, 256, 0, stream>>>(logits, labels, gbins, N);
    ece_final<<<1, 1, 0, stream>>>(gbins, out, N);
}